// Round 4
// baseline (202.417 us; speedup 1.0000x reference)
//
#include <hip/hip_runtime.h>
#include <hip/hip_cooperative_groups.h>
#include <math.h>

namespace cg = cooperative_groups;

#define T_END_F 100.0f
#define N_TAB 4096
#define HID 128
#define EVB 8             // table entries per block (phase A)
#define EVW 2             // table entries per wave (4 waves/block)
#define NBLOCKS 512       // N_TAB/EVB = 512; also phase-B grid
#define N_MC_TOTAL 92160  // 15 * 16 * 384
#define TF_HALF 46080u
#define NSLOT 16

// ---------- math helpers ----------
__device__ __forceinline__ float softplusf(float z){
  return fmaxf(z, 0.0f) + log1pf(expf(-fabsf(z)));
}

__device__ __forceinline__ unsigned rotl32(unsigned x, unsigned d){
  return (x << d) | (x >> (32u - d));
}

// Bit-exact JAX threefry2x32 uniform for key(42), total count 92160.
__device__ float threefry_u01(unsigned idx){
  unsigned i0, i1;
  bool second = idx >= TF_HALF;
  if (second){ i0 = idx - TF_HALF; i1 = idx; }
  else       { i0 = idx;           i1 = idx + TF_HALF; }
  const unsigned ks0 = 0u;
  const unsigned ks1 = 42u;
  const unsigned ks2 = 0x1BD11BDAu ^ ks0 ^ ks1;
  unsigned x0 = i0 + ks0;
  unsigned x1 = i1 + ks1;
#define TF_R(r) { x0 += x1; x1 = rotl32(x1, (r)); x1 ^= x0; }
  TF_R(13) TF_R(15) TF_R(26) TF_R(6)
  x0 += ks1; x1 += ks2 + 1u;
  TF_R(17) TF_R(29) TF_R(16) TF_R(24)
  x0 += ks2; x1 += ks0 + 2u;
  TF_R(13) TF_R(15) TF_R(26) TF_R(6)
  x0 += ks0; x1 += ks1 + 3u;
  TF_R(17) TF_R(29) TF_R(16) TF_R(24)
  x0 += ks1; x1 += ks2 + 4u;
  TF_R(13) TF_R(15) TF_R(26) TF_R(6)
  x0 += ks2; x1 += ks0 + 5u;
#undef TF_R
  unsigned bits = second ? x1 : x0;
  unsigned fb = (bits >> 9) | 0x3F800000u;
  return __uint_as_float(fb) - 1.0f;
}

// linear interp lookup, x in [0, T_END]
__device__ __forceinline__ float table_f(const float* __restrict__ tab, float x){
  float pos = x * ((float)(N_TAB - 1) / T_END_F);
  int i = (int)pos;
  if (i < 0) i = 0;
  if (i > N_TAB - 2) i = N_TAB - 2;
  float fr = pos - (float)i;
  float a = tab[i];
  float b = tab[i + 1];
  return fmaf(fr, b - a, a);
}

// ---------- phase A helper: one dense 128->128 tanh layer ----------
// 4 waves/block, wave owns EVW=2 private LDS rows -> no __syncthreads needed.
__device__ __forceinline__ void dense_tanh_layer(
    const float (*__restrict__ hin)[HID], float (*__restrict__ hout)[HID],
    const float* __restrict__ W, const float* __restrict__ bv,
    int k0, int k1, int ebase)
{
  float acc0[EVW], acc1[EVW];
  {
    float ba = bv[k0], bb = bv[k1];
#pragma unroll
    for (int e = 0; e < EVW; ++e){ acc0[e] = ba; acc1[e] = bb; }
  }
#pragma unroll 4
  for (int j = 0; j < HID; j += 4){
    float wa0 = W[(j+0)*HID + k0];
    float wa1 = W[(j+1)*HID + k0];
    float wa2 = W[(j+2)*HID + k0];
    float wa3 = W[(j+3)*HID + k0];
    float wb0 = W[(j+0)*HID + k1];
    float wb1 = W[(j+1)*HID + k1];
    float wb2 = W[(j+2)*HID + k1];
    float wb3 = W[(j+3)*HID + k1];
#pragma unroll
    for (int e = 0; e < EVW; ++e){
      float4 h = *(const float4*)&hin[ebase + e][j];   // wave-uniform LDS broadcast
      float a0 = acc0[e], a1 = acc1[e];
      a0 = fmaf(h.x, wa0, a0); a1 = fmaf(h.x, wb0, a1);
      a0 = fmaf(h.y, wa1, a0); a1 = fmaf(h.y, wb1, a1);
      a0 = fmaf(h.z, wa2, a0); a1 = fmaf(h.z, wb2, a1);
      a0 = fmaf(h.w, wa3, a0); a1 = fmaf(h.w, wb3, a1);
      acc0[e] = a0; acc1[e] = a1;
    }
  }
#pragma unroll
  for (int e = 0; e < EVW; ++e){
    hout[ebase + e][k0] = tanhf(acc0[e]);
    hout[ebase + e][k1] = tanhf(acc1[e]);
  }
}

// ---------- single cooperative kernel: build table | grid.sync | pairs+MC | finalize ----------
__global__ __launch_bounds__(256) void mcsip_kernel(
    const float* __restrict__ t,        // [16][384] seq_pads
    const int* __restrict__ seq_lens,   // [16]
    const float* __restrict__ bg,
    const float* __restrict__ W1, const float* __restrict__ b1v,
    const float* __restrict__ W2, const float* __restrict__ b2v,
    const float* __restrict__ W3, const float* __restrict__ b3v,
    const float* __restrict__ W4, const float* __restrict__ b4v,
    float* __restrict__ tab,            // [N_TAB] ws
    float* __restrict__ slots,          // [2*NSLOT] ws: logs then mc
    float* __restrict__ out)
{
  cg::grid_group grid = cg::this_grid();

  __shared__ float hA[EVB][HID];
  __shared__ float hB[EVB][HID];
  const int tid  = threadIdx.x;
  const int wv   = tid >> 6;
  const int lane = tid & 63;
  const int k0 = lane, k1 = lane + 64;
  const int ebase = wv * EVW;
  const int base = blockIdx.x * EVB;
  const float dt = T_END_F / (float)(N_TAB - 1);
  const float bgv = bg[0];

  // ---- phase A: build f-table (EVB entries per block) ----
  if (blockIdx.x == 0 && tid < 2 * NSLOT) slots[tid] = 0.0f;

  {
    float wa = W1[k0], wb = W1[k1];
    float ba = b1v[k0], bb = b1v[k1];
#pragma unroll
    for (int e = 0; e < EVW; ++e){
      float x = (float)(base + ebase + e) * dt;
      hA[ebase + e][k0] = tanhf(fmaf(x, wa, ba));
      hA[ebase + e][k1] = tanhf(fmaf(x, wb, bb));
    }
  }
  dense_tanh_layer(hA, hB, W2, b2v, k0, k1, ebase);   // layer 2
  dense_tanh_layer(hB, hA, W3, b3v, k0, k1, ebase);   // layer 3
  {
    float wa = W4[k0], wb = W4[k1];
    float b4s = b4v[0];
#pragma unroll
    for (int e = 0; e < EVW; ++e){
      float p = hA[ebase + e][k0] * wa + hA[ebase + e][k1] * wb;
      p += __shfl_xor(p, 32);
      p += __shfl_xor(p, 16);
      p += __shfl_xor(p, 8);
      p += __shfl_xor(p, 4);
      p += __shfl_xor(p, 2);
      p += __shfl_xor(p, 1);
      if (lane == 0) tab[base + ebase + e] = softplusf(p + b4s);
    }
  }

  grid.sync();   // table complete & visible device-wide

  // ---- phase B: pairs log-sum + MC integral ----
  const int gwave = blockIdx.x * 4 + wv;   // 0..2047
  float logsum = 0.0f;   // meaningful on lane 0 only
  float mcv    = 0.0f;

#pragma unroll
  for (int k = 0; k < 3; ++k){
    unsigned task = (unsigned)gwave + (unsigned)k * 2048u;  // < 6144
    unsigned b = task / 384u;
    int i = (int)(task - b * 384u);
    if (i < seq_lens[b]){
      const float* tb = t + b * 384u;
      float ti = tb[i];
      float s = 0.0f;
      for (int j = lane; j < i; j += 64)
        s += table_f(tab, ti - tb[j]);
      s += __shfl_xor(s, 32);
      s += __shfl_xor(s, 16);
      s += __shfl_xor(s, 8);
      s += __shfl_xor(s, 4);
      s += __shfl_xor(s, 2);
      s += __shfl_xor(s, 1);
      if (lane == 0) logsum += logf(s + bgv);
    }
  }

  {
    int idx = blockIdx.x * 256 + tid;
    if (idx < N_MC_TOTAL){
      int l = idx % 384;
      int b = (idx / 384) & 15;
      if (l < seq_lens[b]){
        float tv = t[b * 384 + l];
        float dl = T_END_F - tv;
        float u  = threefry_u01((unsigned)idx);
        mcv = (table_f(tab, u * dl) + 1e-10f) * dl;
      }
    }
  }
  mcv += __shfl_xor(mcv, 32);
  mcv += __shfl_xor(mcv, 16);
  mcv += __shfl_xor(mcv, 8);
  mcv += __shfl_xor(mcv, 4);
  mcv += __shfl_xor(mcv, 2);
  mcv += __shfl_xor(mcv, 1);

  __shared__ float redL[4], redM[4];
  if (lane == 0){ redL[wv] = logsum; redM[wv] = mcv; }
  __syncthreads();
  if (tid == 0){
    int slot = blockIdx.x & (NSLOT - 1);
    atomicAdd(&slots[slot],         redL[0] + redL[1] + redL[2] + redL[3]);
    atomicAdd(&slots[NSLOT + slot], redM[0] + redM[1] + redM[2] + redM[3]);
  }

  grid.sync();   // all slot atomics complete & visible

  // ---- finalize ----
  if (blockIdx.x == 0 && tid == 0){
    float sl = 0.0f, sm = 0.0f;
    for (int q = 0; q < NSLOT; ++q){
      sl += slots[q];
      sm += slots[NSLOT + q];
    }
    float lamb_ints_total = sm * (1.0f / 15.0f) + 16.0f * T_END_F * bgv;
    out[0] = -(sl - lamb_ints_total) / 16.0f;
  }
}

extern "C" void kernel_launch(void* const* d_in, const int* in_sizes, int n_in,
                              void* d_out, int out_size, void* d_ws, size_t ws_size,
                              hipStream_t stream)
{
  const float* seq_pads = (const float*)d_in[0];
  const int*   seq_lens = (const int*)d_in[1];
  const float* bg       = (const float*)d_in[2];
  const float* W1 = (const float*)d_in[3];
  const float* b1 = (const float*)d_in[4];
  const float* W2 = (const float*)d_in[5];
  const float* b2 = (const float*)d_in[6];
  const float* W3 = (const float*)d_in[7];
  const float* b3 = (const float*)d_in[8];
  const float* W4 = (const float*)d_in[9];
  const float* b4 = (const float*)d_in[10];
  float* out = (float*)d_out;

  float* tab   = (float*)d_ws;          // N_TAB floats
  float* slots = tab + N_TAB;           // 2*NSLOT floats

  void* args[] = {
    (void*)&seq_pads, (void*)&seq_lens, (void*)&bg,
    (void*)&W1, (void*)&b1, (void*)&W2, (void*)&b2,
    (void*)&W3, (void*)&b3, (void*)&W4, (void*)&b4,
    (void*)&tab, (void*)&slots, (void*)&out
  };
  hipLaunchCooperativeKernel((const void*)mcsip_kernel,
                             dim3(NBLOCKS), dim3(256), args, 0, stream);
}

// Round 5
// 112.225 us; speedup vs baseline: 1.8037x; 1.8037x over previous
//
#include <hip/hip_runtime.h>
#include <math.h>

#define T_END_F 100.0f
#define N_TAB 4096
#define HID 128
#define EVB 8             // table entries per block
#define EVW 2             // table entries per wave (4 waves/block)
#define NBLK_TAB (N_TAB / EVB)   // 512 blocks
#define N_MC_TOTAL 92160  // 15 * 16 * 384
#define TF_HALF 46080u
#define FUSED_BLOCKS 512
#define NSLOT 16

// ---------- math helpers ----------
__device__ __forceinline__ float softplusf(float z){
  return fmaxf(z, 0.0f) + log1pf(expf(-fabsf(z)));
}

__device__ __forceinline__ unsigned rotl32(unsigned x, unsigned d){
  return (x << d) | (x >> (32u - d));
}

// Bit-exact JAX threefry2x32 uniform for key(42), total count 92160.
__device__ float threefry_u01(unsigned idx){
  unsigned i0, i1;
  bool second = idx >= TF_HALF;
  if (second){ i0 = idx - TF_HALF; i1 = idx; }
  else       { i0 = idx;           i1 = idx + TF_HALF; }
  const unsigned ks0 = 0u;
  const unsigned ks1 = 42u;
  const unsigned ks2 = 0x1BD11BDAu ^ ks0 ^ ks1;
  unsigned x0 = i0 + ks0;
  unsigned x1 = i1 + ks1;
#define TF_R(r) { x0 += x1; x1 = rotl32(x1, (r)); x1 ^= x0; }
  TF_R(13) TF_R(15) TF_R(26) TF_R(6)
  x0 += ks1; x1 += ks2 + 1u;
  TF_R(17) TF_R(29) TF_R(16) TF_R(24)
  x0 += ks2; x1 += ks0 + 2u;
  TF_R(13) TF_R(15) TF_R(26) TF_R(6)
  x0 += ks0; x1 += ks1 + 3u;
  TF_R(17) TF_R(29) TF_R(16) TF_R(24)
  x0 += ks1; x1 += ks2 + 4u;
  TF_R(13) TF_R(15) TF_R(26) TF_R(6)
  x0 += ks2; x1 += ks0 + 5u;
#undef TF_R
  unsigned bits = second ? x1 : x0;
  unsigned fb = (bits >> 9) | 0x3F800000u;
  return __uint_as_float(fb) - 1.0f;
}

// linear interp lookup, x in [0, T_END]
__device__ __forceinline__ float table_f(const float* __restrict__ tab, float x){
  float pos = x * ((float)(N_TAB - 1) / T_END_F);
  int i = (int)pos;
  if (i < 0) i = 0;
  if (i > N_TAB - 2) i = N_TAB - 2;
  float fr = pos - (float)i;
  float a = tab[i];
  float b = tab[i + 1];
  return fmaf(fr, b - a, a);
}

// ---------- table build ----------
// 256 threads = 4 waves. Each wave owns EVW=2 table entries (private LDS rows,
// no cross-wave deps -> no __syncthreads). All 4 waves stream the same weight
// addresses -> L1 reuse. Thread owns hidden units k0=lane, k1=lane+64.
__device__ __forceinline__ void dense_tanh_layer(
    const float (*__restrict__ hin)[HID], float (*__restrict__ hout)[HID],
    const float* __restrict__ W, const float* __restrict__ bv,
    int k0, int k1, int ebase)
{
  float acc0[EVW], acc1[EVW];
  {
    float ba = bv[k0], bb = bv[k1];
#pragma unroll
    for (int e = 0; e < EVW; ++e){ acc0[e] = ba; acc1[e] = bb; }
  }
#pragma unroll 4
  for (int j = 0; j < HID; j += 4){
    float wa0 = W[(j+0)*HID + k0];
    float wa1 = W[(j+1)*HID + k0];
    float wa2 = W[(j+2)*HID + k0];
    float wa3 = W[(j+3)*HID + k0];
    float wb0 = W[(j+0)*HID + k1];
    float wb1 = W[(j+1)*HID + k1];
    float wb2 = W[(j+2)*HID + k1];
    float wb3 = W[(j+3)*HID + k1];
#pragma unroll
    for (int e = 0; e < EVW; ++e){
      float4 h = *(const float4*)&hin[ebase + e][j];   // wave-uniform LDS broadcast
      float a0 = acc0[e], a1 = acc1[e];
      a0 = fmaf(h.x, wa0, a0); a1 = fmaf(h.x, wb0, a1);
      a0 = fmaf(h.y, wa1, a0); a1 = fmaf(h.y, wb1, a1);
      a0 = fmaf(h.z, wa2, a0); a1 = fmaf(h.z, wb2, a1);
      a0 = fmaf(h.w, wa3, a0); a1 = fmaf(h.w, wb3, a1);
      acc0[e] = a0; acc1[e] = a1;
    }
  }
#pragma unroll
  for (int e = 0; e < EVW; ++e){
    hout[ebase + e][k0] = tanhf(acc0[e]);
    hout[ebase + e][k1] = tanhf(acc1[e]);
  }
}

__global__ __launch_bounds__(256) void build_table_kernel(
    const float* __restrict__ W1, const float* __restrict__ b1v,
    const float* __restrict__ W2, const float* __restrict__ b2v,
    const float* __restrict__ W3, const float* __restrict__ b3v,
    const float* __restrict__ W4, const float* __restrict__ b4v,
    float* __restrict__ tab, float* __restrict__ slots, int* __restrict__ cnt)
{
  __shared__ float hA[EVB][HID];
  __shared__ float hB[EVB][HID];
  const int tid  = threadIdx.x;
  const int wv   = tid >> 6;
  const int lane = tid & 63;
  const int k0 = lane, k1 = lane + 64;
  const int ebase = wv * EVW;
  const int base = blockIdx.x * EVB;
  const float dt = T_END_F / (float)(N_TAB - 1);

  // zero the fused kernel's accumulators (runs-before fused kernel via stream order)
  if (blockIdx.x == 0 && tid < 2 * NSLOT + 1){
    if (tid < 2 * NSLOT) slots[tid] = 0.0f;
    else *cnt = 0;
  }

  // layer 1: scalar -> 128
  {
    float wa = W1[k0], wb = W1[k1];
    float ba = b1v[k0], bb = b1v[k1];
#pragma unroll
    for (int e = 0; e < EVW; ++e){
      float x = (float)(base + ebase + e) * dt;
      hA[ebase + e][k0] = tanhf(fmaf(x, wa, ba));
      hA[ebase + e][k1] = tanhf(fmaf(x, wb, bb));
    }
  }
  dense_tanh_layer(hA, hB, W2, b2v, k0, k1, ebase);   // layer 2
  dense_tanh_layer(hB, hA, W3, b3v, k0, k1, ebase);   // layer 3
  // layer 4: 128 -> 1, softplus
  {
    float wa = W4[k0], wb = W4[k1];
    float b4s = b4v[0];
#pragma unroll
    for (int e = 0; e < EVW; ++e){
      float p = hA[ebase + e][k0] * wa + hA[ebase + e][k1] * wb;
      p += __shfl_xor(p, 32);
      p += __shfl_xor(p, 16);
      p += __shfl_xor(p, 8);
      p += __shfl_xor(p, 4);
      p += __shfl_xor(p, 2);
      p += __shfl_xor(p, 1);
      if (lane == 0) tab[base + ebase + e] = softplusf(p + b4s);
    }
  }
}

// ---------- fused: pairs log-sum + MC integral + finalize ----------
// 512 blocks x 256 threads = 2048 waves.
// Pairs: 6144 (b,i) tasks, 3 per wave. MC: thread-per-sample (131072 >= 92160).
// Block partials -> 16-slot atomics; last block (ticket) finalizes.
__global__ __launch_bounds__(256) void fused_kernel(
    const float* __restrict__ t,        // [16][384]
    const int* __restrict__ seq_lens,   // [16]
    const float* __restrict__ bg,
    const float* __restrict__ tab,
    float* __restrict__ slots,          // [2*NSLOT]: logs then mc
    int* __restrict__ cnt,
    float* __restrict__ out)
{
  const int tid  = threadIdx.x;
  const int lane = tid & 63;
  const int wv   = tid >> 6;
  const int gwave = blockIdx.x * 4 + wv;   // 0..2047
  const float bgv = bg[0];

  float logsum = 0.0f;   // only lane 0 accumulates
  float mcv    = 0.0f;

  // pairs: tasks gwave, gwave+2048, gwave+4096
#pragma unroll
  for (int k = 0; k < 3; ++k){
    unsigned task = (unsigned)gwave + (unsigned)k * 2048u;  // < 6144
    unsigned b = task / 384u;
    int i = (int)(task - b * 384u);
    if (i < seq_lens[b]){
      const float* tb = t + b * 384u;
      float ti = tb[i];
      float s = 0.0f;
      for (int j = lane; j < i; j += 64)
        s += table_f(tab, ti - tb[j]);
      s += __shfl_xor(s, 32);
      s += __shfl_xor(s, 16);
      s += __shfl_xor(s, 8);
      s += __shfl_xor(s, 4);
      s += __shfl_xor(s, 2);
      s += __shfl_xor(s, 1);
      if (lane == 0) logsum += logf(s + bgv);
    }
  }

  // Monte Carlo sample
  {
    int idx = blockIdx.x * 256 + tid;
    if (idx < N_MC_TOTAL){
      int l = idx % 384;
      int b = (idx / 384) & 15;
      if (l < seq_lens[b]){
        float tv = t[b * 384 + l];
        float dl = T_END_F - tv;
        float u  = threefry_u01((unsigned)idx);
        mcv = (table_f(tab, u * dl) + 1e-10f) * dl;
      }
    }
  }
  mcv += __shfl_xor(mcv, 32);
  mcv += __shfl_xor(mcv, 16);
  mcv += __shfl_xor(mcv, 8);
  mcv += __shfl_xor(mcv, 4);
  mcv += __shfl_xor(mcv, 2);
  mcv += __shfl_xor(mcv, 1);

  __shared__ float redL[4], redM[4];
  if (lane == 0){ redL[wv] = logsum; redM[wv] = mcv; }
  __syncthreads();
  if (tid == 0){
    float bl = redL[0] + redL[1] + redL[2] + redL[3];
    float bm = redM[0] + redM[1] + redM[2] + redM[3];
    int slot = blockIdx.x & (NSLOT - 1);
    atomicAdd(&slots[slot], bl);
    atomicAdd(&slots[NSLOT + slot], bm);
    __threadfence();
    int old = atomicAdd(cnt, 1);
    if (old == (int)gridDim.x - 1){
      // last block: atomic-RMW reads guarantee device-coherent values
      float sl = 0.0f, sm = 0.0f;
      for (int q = 0; q < NSLOT; ++q){
        sl += atomicAdd(&slots[q], 0.0f);
        sm += atomicAdd(&slots[NSLOT + q], 0.0f);
      }
      float lamb_ints_total = sm * (1.0f / 15.0f) + 16.0f * T_END_F * bgv;
      out[0] = -(sl - lamb_ints_total) / 16.0f;
    }
  }
}

extern "C" void kernel_launch(void* const* d_in, const int* in_sizes, int n_in,
                              void* d_out, int out_size, void* d_ws, size_t ws_size,
                              hipStream_t stream)
{
  const float* seq_pads = (const float*)d_in[0];
  const int*   seq_lens = (const int*)d_in[1];
  const float* bg       = (const float*)d_in[2];
  const float* W1 = (const float*)d_in[3];
  const float* b1 = (const float*)d_in[4];
  const float* W2 = (const float*)d_in[5];
  const float* b2 = (const float*)d_in[6];
  const float* W3 = (const float*)d_in[7];
  const float* b3 = (const float*)d_in[8];
  const float* W4 = (const float*)d_in[9];
  const float* b4 = (const float*)d_in[10];
  float* out = (float*)d_out;

  float* tab   = (float*)d_ws;          // N_TAB floats
  float* slots = tab + N_TAB;           // 2*NSLOT floats
  int*   cnt   = (int*)(slots + 2 * NSLOT);

  build_table_kernel<<<NBLK_TAB, 256, 0, stream>>>(W1, b1, W2, b2, W3, b3, W4, b4,
                                                   tab, slots, cnt);
  fused_kernel<<<FUSED_BLOCKS, 256, 0, stream>>>(seq_pads, seq_lens, bg, tab,
                                                 slots, cnt, out);
}